// Round 1
// baseline (693.371 us; speedup 1.0000x reference)
//
#include <hip/hip_runtime.h>
#include <math.h>

#define VOLN 256
#define N_ANG 16
#define DET_V 128
#define DET_U 128
#define DET_SP 5.0
#define DSI 400.0
#define DSD 800.0
#define N_STEP 192

// radius = sqrt(3)*256/2 ; t0 = DSI - radius ; dt = 2*radius/N_STEP  (fp32-rounded like the reference)
#define T0_F 178.29749663118372f
#define DT_F 2.3094010767585029f

__device__ __forceinline__ float trilerp(const float* __restrict__ vol,
                                         float pz, float py, float px) {
    float z0f = floorf(pz), y0f = floorf(py), x0f = floorf(px);
    int z0 = (int)z0f, y0 = (int)y0f, x0 = (int)x0f;
    float fz = pz - z0f, fy = py - y0f, fx = px - x0f;

    // Fast path: whole 2x2x2 cell strictly in bounds.
    if (z0 >= 0 && z0 <= VOLN - 2 && y0 >= 0 && y0 <= VOLN - 2 && x0 >= 0 && x0 <= VOLN - 2) {
        const float* base = vol + (((z0 << 8) + y0) << 8) + x0;
        float v000 = base[0];
        float v001 = base[1];
        float v010 = base[VOLN];
        float v011 = base[VOLN + 1];
        float v100 = base[VOLN * VOLN];
        float v101 = base[VOLN * VOLN + 1];
        float v110 = base[VOLN * VOLN + VOLN];
        float v111 = base[VOLN * VOLN + VOLN + 1];
        float c00 = fmaf(fx, v001 - v000, v000);
        float c01 = fmaf(fx, v011 - v010, v010);
        float c10 = fmaf(fx, v101 - v100, v100);
        float c11 = fmaf(fx, v111 - v110, v110);
        float c0 = fmaf(fy, c01 - c00, c00);
        float c1 = fmaf(fy, c11 - c10, c10);
        return fmaf(fz, c1 - c0, c0);
    }

    // Entirely outside?
    if (z0 < -1 || z0 > VOLN - 1 || y0 < -1 || y0 > VOLN - 1 || x0 < -1 || x0 > VOLN - 1)
        return 0.0f;

    // Slow path: per-corner bounds mask (zero outside), matches reference semantics.
    float acc = 0.0f;
    #pragma unroll
    for (int dz = 0; dz < 2; ++dz) {
        int iz = z0 + dz;
        if (iz < 0 || iz > VOLN - 1) continue;
        float wz = dz ? fz : (1.0f - fz);
        #pragma unroll
        for (int dy = 0; dy < 2; ++dy) {
            int iy = y0 + dy;
            if (iy < 0 || iy > VOLN - 1) continue;
            float wy = dy ? fy : (1.0f - fy);
            #pragma unroll
            for (int dx = 0; dx < 2; ++dx) {
                int ix = x0 + dx;
                if (ix < 0 || ix > VOLN - 1) continue;
                float wx = dx ? fx : (1.0f - fx);
                float v = vol[(((iz << 8) + iy) << 8) + ix];
                acc = fmaf(wz * wy * wx, v, acc);
            }
        }
    }
    return acc;
}

__global__ __launch_bounds__(256) void cone_proj_kernel(const float* __restrict__ vol,
                                                        float* __restrict__ out) {
    int idx = blockIdx.x * blockDim.x + threadIdx.x;   // [0, N_ANG*DET_V*DET_U)
    int u = idx & (DET_U - 1);
    int v = (idx >> 7) & (DET_V - 1);
    int a = idx >> 14;

    // Per-ray geometry in double (once), march in fp32.
    double theta = (2.0 * M_PI / (double)N_ANG) * (double)a;
    double cth = cos(theta), sth = sin(theta);
    double uoff = ((double)u - (DET_U - 1) * 0.5) * DET_SP;
    double voff = ((double)v - (DET_V - 1) * 0.5) * DET_SP;

    // dir (unnormalized) = det - src = (voff, -DSD*s + uoff*c, -DSD*c - uoff*s); |dir| = sqrt(voff^2+uoff^2+DSD^2)
    double dzd = voff;
    double dyd = -DSD * sth + uoff * cth;
    double dxd = -DSD * cth - uoff * sth;
    double inv = 1.0 / sqrt(uoff * uoff + voff * voff + DSD * DSD);

    float dirz = (float)(dzd * inv);
    float diry = (float)(dyd * inv);
    float dirx = (float)(dxd * inv);
    float srcz = 0.0f;
    float srcy = (float)(DSI * sth);
    float srcx = (float)(DSI * cth);

    const float half = (VOLN - 1) * 0.5f;
    float bz = srcz + half, by = srcy + half, bx = srcx + half;

    float acc = 0.0f;
    for (int i = 0; i < N_STEP; ++i) {
        float t = fmaf((float)i + 0.5f, DT_F, T0_F);
        float pz = fmaf(t, dirz, bz);
        float py = fmaf(t, diry, by);
        float px = fmaf(t, dirx, bx);
        acc += trilerp(vol, pz, py, px);
    }
    out[idx] = acc * DT_F;
}

extern "C" void kernel_launch(void* const* d_in, const int* in_sizes, int n_in,
                              void* d_out, int out_size, void* d_ws, size_t ws_size,
                              hipStream_t stream) {
    const float* vol = (const float*)d_in[0];
    float* out = (float*)d_out;
    int total = N_ANG * DET_V * DET_U;   // == out_size
    dim3 block(256);
    dim3 grid((total + 255) / 256);
    cone_proj_kernel<<<grid, block, 0, stream>>>(vol, out);
}